// Round 11
// baseline (182.510 us; speedup 1.0000x reference)
//
#include <hip/hip_runtime.h>
#include <stdint.h>
#include <stddef.h>

// GCCN: h1 = relu(x @ W1); h2 = relu(geo(h1, Wg1) + b1); res = geo(h2, Wg2) + b2; out = res/|res|
// geo(h, Wg)[n,o] = sum_b sum_i h[conn[n,b], i] * Wg[b,i,o]   (gathered GEMM, K = 80*64)
//
// Round-11: (A) conn pinned in regs via keep-alive asm (kills per-bin compiler
// vmcnt(0) drains that serialized r10's pipeline); (B) layer-1 source-range split
// C=2 (grid z, temporal) with out-of-range conn clamped to a zeroed row n ->
// each XCD's gather working set is 1.92MB -> L2-resident. 8 partial pieces/layer.

typedef __attribute__((ext_vector_type(8))) short bf16x8;
typedef __attribute__((ext_vector_type(4))) float f32x4;

#define BINS 80
#define PIECES 8         // partial pieces per layer (L1: 4 bin-chunks x 2 ranges; L2: 8 x 1)
#define PFD 5            // gather prefetch depth (bins ahead)

static __device__ __forceinline__ unsigned short f2bf(float f) {
  union { float f; unsigned int u; } c; c.f = f;
  unsigned int u = c.u;
  return (unsigned short)((u + 0x7FFFu + ((u >> 16) & 1u)) >> 16);
}

static __device__ __forceinline__ void wait_vm(int m) {
  if (m >= 10)      asm volatile("s_waitcnt vmcnt(10)");
  else if (m == 8)  asm volatile("s_waitcnt vmcnt(8)");
  else if (m == 6)  asm volatile("s_waitcnt vmcnt(6)");
  else if (m == 4)  asm volatile("s_waitcnt vmcnt(4)");
  else if (m == 2)  asm volatile("s_waitcnt vmcnt(2)");
  else              asm volatile("s_waitcnt vmcnt(0)");
}

// ------- linear_1: h1[v][64] = relu(x[v][0:16] @ W1) as bf16; row n zeroed -------
__global__ __launch_bounds__(256) void k_lin1(const float* __restrict__ x,
                                              const float* __restrict__ W1,
                                              unsigned short* __restrict__ h1b, int n) {
  __shared__ float w1s[16 * 64];
  int tid = threadIdx.x;
  for (int i = tid; i < 16 * 64; i += 256) w1s[i] = W1[i];
  __syncthreads();
  int v = blockIdx.x * 256 + tid;
  if (v > n) return;
  unsigned short* hr = h1b + (size_t)v * 64;
  if (v == n) {                       // zero row for range-clamped gathers
    bf16x8 z = (bf16x8){0,0,0,0,0,0,0,0};
#pragma unroll
    for (int o8 = 0; o8 < 8; ++o8) *(bf16x8*)(hr + o8 * 8) = z;
    return;
  }
  const float4* xp = (const float4*)(x + (size_t)v * 16);
  float4 x0 = xp[0], x1 = xp[1], x2 = xp[2], x3 = xp[3];
  float xr[16] = {x0.x, x0.y, x0.z, x0.w, x1.x, x1.y, x1.z, x1.w,
                  x2.x, x2.y, x2.z, x2.w, x3.x, x3.y, x3.z, x3.w};
  float acc[64];
#pragma unroll
  for (int o = 0; o < 64; ++o) acc[o] = 0.f;
#pragma unroll
  for (int i = 0; i < 16; ++i) {
    float xi = xr[i];
#pragma unroll
    for (int o = 0; o < 64; ++o) acc[o] = fmaf(xi, w1s[i * 64 + o], acc[o]);
  }
#pragma unroll
  for (int o8 = 0; o8 < 8; ++o8) {
    bf16x8 pack;
#pragma unroll
    for (int j = 0; j < 8; ++j) pack[j] = (short)f2bf(fmaxf(acc[o8 * 8 + j], 0.f));
    *(bf16x8*)(hr + o8 * 8) = pack;
  }
}

// ---- weight image: Wg[b][i][o] f32 -> img[b][z][o][chunk] bf16, chunk-permuted ----
// byte(b,z,o,j) = b*(O*128) + z*(O*64) + o*64 + ((j+(o>>1))&3)*16
__global__ __launch_bounds__(256) void k_wimg(const float* __restrict__ Wg,
                                              unsigned char* __restrict__ img,
                                              int O, int total) {
  int t = blockIdx.x * 256 + threadIdx.x;
  if (t >= total) return;                 // total = 80 * 2 * O * 4
  int j = t & 3;
  int r = t >> 2;
  int o = r % O;
  int r2 = r / O;
  int z = r2 & 1;
  int b = r2 >> 1;
  bf16x8 pack;
#pragma unroll
  for (int tt = 0; tt < 8; ++tt)
    pack[tt] = (short)f2bf(Wg[(size_t)(b * 64 + z * 32 + j * 8 + tt) * O + o]);
  size_t boff = (size_t)b * (O * 128) + z * (O * 64) + o * 64 + ((j + (o >> 1)) & 3) * 16;
  *(bf16x8*)(img + boff) = pack;
}

// --------- geodesic layer: i-half phases, reg-conn (pinned), range-clamped gathers ---------
// grid (vt, SPLITKy, RANGES); block 512 = 8 waves; wave owns rows [v0+w*32,+32), all O cols.
// Sources outside [z*hn, z*hn+hn) are clamped to zero-row n at cpk-pack time.
template <int OT, int BPCT>   // O = OT*16; per-bin per-phase slab = OT*1024 bytes
__global__ __launch_bounds__(512, 4) void k_geo4(const unsigned short* __restrict__ hin,
                                                 const unsigned char* __restrict__ wimg,
                                                 const int* __restrict__ conn,
                                                 float* __restrict__ part, int n, int hn) {
  constexpr int SLAB = OT * 1024;
  constexpr int TOT = BPCT * SLAB;            // bytes per phase
  constexpr int RR = (TOT + 8191) / 8192;     // ceil staging rounds (512 thr x 16B)
  __shared__ alignas(16) unsigned char wg_s[TOT];

  const int tid = threadIdx.x;
  const int lane = tid & 63;
  const int wave = tid >> 6;
  const int ln15 = lane & 15;
  const int lq = lane >> 4;                   // 0..3
  const int v0 = blockIdx.x * 256;
  const int bin0 = blockIdx.y * BPCT;
  const int lo = blockIdx.z * hn;
  const unsigned range = (unsigned)((lo + hn > n ? n : lo + hn) - lo);

  int vv0 = v0 + wave * 32 + ln15;      if (vv0 > n - 1) vv0 = n - 1;
  int vv1 = v0 + wave * 32 + 16 + ln15; if (vv1 > n - 1) vv1 = n - 1;

  auto stage = [&](int ph) {
#pragma unroll
    for (int r = 0; r < RR; ++r) {
      int off = (r * 512 + tid) * 16;
      if (off < TOT) {                        // folds away when 8192 | TOT
        int bin = off / SLAB;
        int within = off & (SLAB - 1);
        __builtin_amdgcn_global_load_lds(
            (const __attribute__((address_space(1))) unsigned int*)(const void*)
                (wimg + (size_t)(bin0 + bin) * (2 * SLAB) + ph * SLAB + within),
            (__attribute__((address_space(3))) unsigned int*)(void*)(wg_s + off),
            16, 0, 0);
      }
    }
  };

  stage(0);

  // conn -> packed regs (2x16b per VGPR), out-of-range clamped to zero-row n.
  unsigned int cpk[BPCT];
#pragma unroll
  for (int j = 0; j < BPCT; ++j) {
    int c0 = conn[(size_t)vv0 * BINS + bin0 + j];
    int c1 = conn[(size_t)vv1 * BINS + bin0 + j];
    if ((unsigned)(c0 - lo) >= range) c0 = n;
    if ((unsigned)(c1 - lo) >= range) c1 = n;
    cpk[j] = ((unsigned)c0 & 0xffffu) | ((unsigned)c1 << 16);
  }
  // keep-alive: force materialization NOW (compiler emits its waitcnt here, once),
  // so no conn loads / waits appear inside the counted pipeline region (rule #17).
#pragma unroll
  for (int j = 0; j < BPCT; ++j) asm volatile("" :: "v"(cpk[j]));
  __builtin_amdgcn_sched_barrier(0);

  // per-lane B-fragment byte offsets (chunk-permuted; constant across bins/phases)
  int boffs[OT];
#pragma unroll
  for (int ot = 0; ot < OT; ++ot) {
    int o = ot * 16 + ln15;
    boffs[ot] = o * 64 + ((lq + (o >> 1)) & 3) * 16;
  }

  const int koff = lq * 8;                    // elements within the 32-i half

  bf16x8 As[6][2];                            // pinned by asm outputs; %6 static after unroll
  f32x4 acc[2][OT];
#pragma unroll
  for (int mt = 0; mt < 2; ++mt)
#pragma unroll
    for (int ot = 0; ot < OT; ++ot) acc[mt][ot] = (f32x4){0.f, 0.f, 0.f, 0.f};

#define ISSUE(ph, j) do {                                                        \
    int c0_ = (int)(cpk[(j)] & 0xffffu);                                         \
    int c1_ = (int)(cpk[(j)] >> 16);                                             \
    const void* p0_ = (const void*)(hin + (size_t)c0_ * 64 + (ph) * 32 + koff);  \
    const void* p1_ = (const void*)(hin + (size_t)c1_ * 64 + (ph) * 32 + koff);  \
    asm volatile("global_load_dwordx4 %0, %1, off" : "=v"(As[(j) % 6][0]) : "v"(p0_)); \
    asm volatile("global_load_dwordx4 %0, %1, off" : "=v"(As[(j) % 6][1]) : "v"(p1_)); \
  } while (0)

  auto run_phase = [&](int ph) {
#pragma unroll
    for (int b = 0; b < BPCT; ++b) {
      if (b + PFD < BPCT) ISSUE(ph, b + PFD);
      int rem = BPCT - 1 - b;
      wait_vm(2 * (rem > PFD ? PFD : rem));   // bin b's 2 loads retired; deeper stay in flight
      __builtin_amdgcn_sched_barrier(0);      // rule #18
      const unsigned char* wb = wg_s + b * SLAB;
#pragma unroll
      for (int ot = 0; ot < OT; ++ot) {
        bf16x8 bf = *(const bf16x8*)(wb + boffs[ot]);
        acc[0][ot] = __builtin_amdgcn_mfma_f32_16x16x32_bf16(As[b % 6][0], bf, acc[0][ot], 0, 0, 0);
        acc[1][ot] = __builtin_amdgcn_mfma_f32_16x16x32_bf16(As[b % 6][1], bf, acc[1][ot], 0, 0, 0);
      }
    }
  };

  // ---- phase 0 ----
#pragma unroll
  for (int j = 0; j < PFD; ++j) ISSUE(0, j);
  wait_vm(2 * PFD);    // gathers are the newest 10 -> staging (+ conn) drained
  __builtin_amdgcn_s_barrier();
  __builtin_amdgcn_sched_barrier(0);
  run_phase(0);

  // ---- transition: all waves done reading wg_s(z0); restage z1 ----
  asm volatile("s_waitcnt lgkmcnt(0)" ::: "memory");
  __builtin_amdgcn_s_barrier();
  __builtin_amdgcn_sched_barrier(0);
  stage(1);
#pragma unroll
  for (int j = 0; j < PFD; ++j) ISSUE(1, j);
  wait_vm(2 * PFD);    // stage(1) drained; 10 gathers in flight
  __builtin_amdgcn_s_barrier();
  __builtin_amdgcn_sched_barrier(0);
  run_phase(1);
#undef ISSUE

  // write f32 partials; piece = z*gridDim.y + y
  constexpr int O = OT * 16;
  float* pbase = part + (size_t)(blockIdx.z * gridDim.y + blockIdx.y) * n * O;
#pragma unroll
  for (int mt = 0; mt < 2; ++mt)
#pragma unroll
    for (int ot = 0; ot < OT; ++ot)
#pragma unroll
      for (int r = 0; r < 4; ++r) {
        int v = v0 + wave * 32 + mt * 16 + lq * 4 + r;
        if (v < n) pbase[(size_t)v * O + ot * 16 + ln15] = acc[mt][ot][r];
      }
}

// ---------------- finalize GC1: sum 8 partials + bias, relu, bf16 ----------------
__global__ __launch_bounds__(256) void k_fin1(const float* __restrict__ part,
                                              const float* __restrict__ bias,
                                              unsigned short* __restrict__ out, int n) {
  int t = blockIdx.x * 256 + threadIdx.x;
  int total = n * 16;                     // groups of 4 outputs
  if (t >= total) return;
  int base = t * 4;
  int o = base & 63;
  size_t stride = (size_t)n * 64;
  const float* p = part + base;
  f32x4 s = *(const f32x4*)(p);
#pragma unroll
  for (int c = 1; c < PIECES; ++c) {
    f32x4 q = *(const f32x4*)(p + c * stride);
    s += q;
  }
  const float* b4 = bias + o;
  ushort4 pack;
  pack.x = f2bf(fmaxf(s[0] + b4[0], 0.f));
  pack.y = f2bf(fmaxf(s[1] + b4[1], 0.f));
  pack.z = f2bf(fmaxf(s[2] + b4[2], 0.f));
  pack.w = f2bf(fmaxf(s[3] + b4[3], 0.f));
  *(ushort4*)(out + base) = pack;
}

// ---------------- finalize GC2: sum 8 partials + bias, normalize ----------------
__global__ __launch_bounds__(256) void k_fin2(const float* __restrict__ part,
                                              const float* __restrict__ bias,
                                              float* __restrict__ out, int n) {
  int v = blockIdx.x * 16 + (threadIdx.x >> 4);
  int o = threadIdx.x & 15;
  if (v >= n) return;
  size_t stride = (size_t)n * 32;
  const float* p = part + (size_t)v * 32 + o;
  float a = 0.f, b = 0.f;
#pragma unroll
  for (int c = 0; c < PIECES; ++c) {
    a += p[c * stride];
    b += p[c * stride + 16];
  }
  a += bias[o];
  b += bias[o + 16];
  float ss = a * a + b * b;
  ss += __shfl_xor(ss, 1);
  ss += __shfl_xor(ss, 2);
  ss += __shfl_xor(ss, 4);
  ss += __shfl_xor(ss, 8);
  float inv = 1.0f / sqrtf(ss);
  out[(size_t)v * 32 + o] = a * inv;
  out[(size_t)v * 32 + 16 + o] = b * inv;
}

extern "C" void kernel_launch(void* const* d_in, const int* in_sizes, int n_in,
                              void* d_out, int out_size, void* d_ws, size_t ws_size,
                              hipStream_t stream) {
  const float* x   = (const float*)d_in[0];
  const float* W1  = (const float*)d_in[1];
  const float* Wg1 = (const float*)d_in[2];
  const float* b1  = (const float*)d_in[3];
  const float* Wg2 = (const float*)d_in[4];
  const float* b2  = (const float*)d_in[5];
  const int*  conn = (const int*)d_in[6];
  int n = in_sizes[0] / 16;

  unsigned char* ws = (unsigned char*)d_ws;
  size_t hb = (((size_t)n + 1) * 64 * 2 + 255) & ~(size_t)255;  // n+1 rows (zero row)
  unsigned short* h1b = (unsigned short*)(ws);
  unsigned short* h2b = (unsigned short*)(ws + hb);
  unsigned char*  w1i = ws + 2 * hb;                        // 80 * 8192
  unsigned char*  w2i = ws + 2 * hb + 80 * 8192;            // 80 * 4096
  float* part = (float*)(ws + 2 * hb + 80 * 8192 + 80 * 4096);  // 8 pieces x n x 64 f32 max

  k_wimg<<<(80 * 2 * 64 * 4 + 255) / 256, 256, 0, stream>>>(Wg1, w1i, 64, 80 * 2 * 64 * 4);
  k_wimg<<<(80 * 2 * 32 * 4 + 255) / 256, 256, 0, stream>>>(Wg2, w2i, 32, 80 * 2 * 32 * 4);
  k_lin1<<<(n + 1 + 255) / 256, 256, 0, stream>>>(x, W1, h1b, n);

  int vt = (n + 255) / 256;
  // layer 1: 4 bin-chunks x 2 source ranges (z slowest -> temporal L2 partitioning)
  k_geo4<4, 20><<<dim3(vt, 4, 2), 512, 0, stream>>>(h1b, w1i, conn, part, n, (n + 1) / 2);
  k_fin1<<<(n * 16 + 255) / 256, 256, 0, stream>>>(part, b1, h2b, n);
  // layer 2: 8 bin-chunks, no range split (h2 table = 1.92MB, L2-resident)
  k_geo4<2, 10><<<dim3(vt, 8, 1), 512, 0, stream>>>(h2b, w2i, conn, part, n, n);
  k_fin2<<<(n + 15) / 16, 256, 0, stream>>>(part, b2, (float*)d_out, n);
}

// Round 12
// 138.264 us; speedup vs baseline: 1.3200x; 1.3200x over previous
//
#include <hip/hip_runtime.h>
#include <stdint.h>
#include <stddef.h>

// GCCN: h1 = relu(x @ W1); h2 = relu(geo(h1, Wg1) + b1); res = geo(h2, Wg2) + b2; out = res/|res|
// geo(h, Wg)[n,o] = sum_b sum_i h[conn[n,b], i] * Wg[b,i,o]   (gathered GEMM, K = 80*64)
//
// Round-12: r6-proven structure (conn in LDS + asm-pinned counted pipeline) with
// LDS shrunk for 2 blocks/CU: conn packed u32 (2x16b) stride-17 (8.7KB), BPC 16 /
// SPLITK 5 for L1 (wg_s 64KB), BPC 10 / SPLITK 8 for L2 (25.6KB -> 4 blocks/CU).
// i-half phases, chunk-permuted weight image, PFD=5 gather prefetch, counted vmcnt.

typedef __attribute__((ext_vector_type(8))) short bf16x8;
typedef __attribute__((ext_vector_type(4))) float f32x4;

#define BINS 80
#define PFD 5            // gather prefetch depth (bins ahead)

static __device__ __forceinline__ unsigned short f2bf(float f) {
  union { float f; unsigned int u; } c; c.f = f;
  unsigned int u = c.u;
  return (unsigned short)((u + 0x7FFFu + ((u >> 16) & 1u)) >> 16);
}

static __device__ __forceinline__ void wait_vm(int m) {
  if (m >= 10)      asm volatile("s_waitcnt vmcnt(10)");
  else if (m == 8)  asm volatile("s_waitcnt vmcnt(8)");
  else if (m == 6)  asm volatile("s_waitcnt vmcnt(6)");
  else if (m == 4)  asm volatile("s_waitcnt vmcnt(4)");
  else if (m == 2)  asm volatile("s_waitcnt vmcnt(2)");
  else              asm volatile("s_waitcnt vmcnt(0)");
}

// ---------------- linear_1: h1[v][64] = relu(x[v][0:16] @ W1) as bf16 ----------------
__global__ __launch_bounds__(256) void k_lin1(const float* __restrict__ x,
                                              const float* __restrict__ W1,
                                              unsigned short* __restrict__ h1b, int n) {
  __shared__ float w1s[16 * 64];
  int tid = threadIdx.x;
  for (int i = tid; i < 16 * 64; i += 256) w1s[i] = W1[i];
  __syncthreads();
  int v = blockIdx.x * 256 + tid;
  if (v >= n) return;
  const float4* xp = (const float4*)(x + (size_t)v * 16);
  float4 x0 = xp[0], x1 = xp[1], x2 = xp[2], x3 = xp[3];
  float xr[16] = {x0.x, x0.y, x0.z, x0.w, x1.x, x1.y, x1.z, x1.w,
                  x2.x, x2.y, x2.z, x2.w, x3.x, x3.y, x3.z, x3.w};
  float acc[64];
#pragma unroll
  for (int o = 0; o < 64; ++o) acc[o] = 0.f;
#pragma unroll
  for (int i = 0; i < 16; ++i) {
    float xi = xr[i];
#pragma unroll
    for (int o = 0; o < 64; ++o) acc[o] = fmaf(xi, w1s[i * 64 + o], acc[o]);
  }
  unsigned short* hr = h1b + (size_t)v * 64;
#pragma unroll
  for (int o8 = 0; o8 < 8; ++o8) {
    bf16x8 pack;
#pragma unroll
    for (int j = 0; j < 8; ++j) pack[j] = (short)f2bf(fmaxf(acc[o8 * 8 + j], 0.f));
    *(bf16x8*)(hr + o8 * 8) = pack;
  }
}

// ---- weight image: Wg[b][i][o] f32 -> img[b][z][o][chunk] bf16, chunk-permuted ----
// byte(b,z,o,j) = b*(O*128) + z*(O*64) + o*64 + ((j+(o>>1))&3)*16
__global__ __launch_bounds__(256) void k_wimg(const float* __restrict__ Wg,
                                              unsigned char* __restrict__ img,
                                              int O, int total) {
  int t = blockIdx.x * 256 + threadIdx.x;
  if (t >= total) return;                 // total = 80 * 2 * O * 4
  int j = t & 3;
  int r = t >> 2;
  int o = r % O;
  int r2 = r / O;
  int z = r2 & 1;
  int b = r2 >> 1;
  bf16x8 pack;
#pragma unroll
  for (int tt = 0; tt < 8; ++tt)
    pack[tt] = (short)f2bf(Wg[(size_t)(b * 64 + z * 32 + j * 8 + tt) * O + o]);
  size_t boff = (size_t)b * (O * 128) + z * (O * 64) + o * 64 + ((j + (o >> 1)) & 3) * 16;
  *(bf16x8*)(img + boff) = pack;
}

// --------- geodesic layer: i-half phases, conn packed in LDS, pinned gather pipeline ---------
// grid (vt, SPLITK); block 512 = 8 waves; wave owns rows [v0+w*32,+32) (2 m-tiles), all O cols.
template <int OT, int BPCT>   // O = OT*16; per-bin per-phase slab = OT*1024 bytes
__global__ __launch_bounds__(512, 4) void k_geo5(const unsigned short* __restrict__ hin,
                                                 const unsigned char* __restrict__ wimg,
                                                 const int* __restrict__ conn,
                                                 float* __restrict__ part, int n) {
  constexpr int SLAB = OT * 1024;
  constexpr int TOT = BPCT * SLAB;            // bytes per phase
  constexpr int RR = (TOT + 8191) / 8192;     // ceil staging rounds (512 thr x 16B)
  constexpr int CP = BPCT + 1;                // padded conn stride (u32 words)
  __shared__ alignas(16) unsigned char wg_s[TOT];
  __shared__ unsigned int conn_ps[128 * CP];  // [pair p = wave*16+ln15][bin], c0|c1<<16

  const int tid = threadIdx.x;
  const int lane = tid & 63;
  const int wave = tid >> 6;
  const int ln15 = lane & 15;
  const int lq = lane >> 4;                   // 0..3
  const int v0 = blockIdx.x * 256;
  const int bin0 = blockIdx.y * BPCT;

  auto stage = [&](int ph) {
#pragma unroll
    for (int r = 0; r < RR; ++r) {
      int off = (r * 512 + tid) * 16;
      if (off < TOT) {                        // folds away when 8192 | TOT
        int bin = off / SLAB;
        int within = off & (SLAB - 1);
        __builtin_amdgcn_global_load_lds(
            (const __attribute__((address_space(1))) unsigned int*)(const void*)
                (wimg + (size_t)(bin0 + bin) * (2 * SLAB) + ph * SLAB + within),
            (__attribute__((address_space(3))) unsigned int*)(void*)(wg_s + off),
            16, 0, 0);
      }
    }
  };

  stage(0);

  // stage conn slice: 128 pairs x BPCT bins, packed (c0 | c1<<16), coalesced reads
  for (int t = tid; t < 128 * BPCT; t += 512) {
    int p = t / BPCT;
    int b = t - p * BPCT;
    int l = p & 15;
    int w = p >> 4;
    int r0 = v0 + w * 32 + l;      if (r0 > n - 1) r0 = n - 1;
    int r1 = r0 + 16;              if (r1 > n - 1) r1 = n - 1;
    unsigned c0 = (unsigned)conn[(size_t)r0 * BINS + bin0 + b];
    unsigned c1 = (unsigned)conn[(size_t)r1 * BINS + bin0 + b];
    conn_ps[p * CP + b] = (c0 & 0xffffu) | (c1 << 16);
  }

  // per-lane B-fragment byte offsets (chunk-permuted; constant across bins/phases)
  int boffs[OT];
#pragma unroll
  for (int ot = 0; ot < OT; ++ot) {
    int o = ot * 16 + ln15;
    boffs[ot] = o * 64 + ((lq + (o >> 1)) & 3) * 16;
  }

  const int koff = lq * 8;                    // elements within the 32-i half
  const int crow = (wave * 16 + ln15) * CP;   // this lane's conn pair row

  bf16x8 As[6][2];                            // pinned by asm outputs; %6 static after unroll
  f32x4 acc[2][OT];
#pragma unroll
  for (int mt = 0; mt < 2; ++mt)
#pragma unroll
    for (int ot = 0; ot < OT; ++ot) acc[mt][ot] = (f32x4){0.f, 0.f, 0.f, 0.f};

#define ISSUE(ph, j) do {                                                        \
    unsigned pk_ = conn_ps[crow + (j)];                                          \
    int c0_ = (int)(pk_ & 0xffffu);                                              \
    int c1_ = (int)(pk_ >> 16);                                                  \
    const void* p0_ = (const void*)(hin + (size_t)c0_ * 64 + (ph) * 32 + koff);  \
    const void* p1_ = (const void*)(hin + (size_t)c1_ * 64 + (ph) * 32 + koff);  \
    asm volatile("global_load_dwordx4 %0, %1, off" : "=v"(As[(j) % 6][0]) : "v"(p0_)); \
    asm volatile("global_load_dwordx4 %0, %1, off" : "=v"(As[(j) % 6][1]) : "v"(p1_)); \
  } while (0)

  auto run_phase = [&](int ph) {
#pragma unroll
    for (int b = 0; b < BPCT; ++b) {
      if (b + PFD < BPCT) ISSUE(ph, b + PFD);
      int rem = BPCT - 1 - b;
      wait_vm(2 * (rem > PFD ? PFD : rem));   // bin b's 2 loads retired; deeper stay in flight
      __builtin_amdgcn_sched_barrier(0);      // rule #18
      const unsigned char* wb = wg_s + b * SLAB;
#pragma unroll
      for (int ot = 0; ot < OT; ++ot) {
        bf16x8 bf = *(const bf16x8*)(wb + boffs[ot]);
        acc[0][ot] = __builtin_amdgcn_mfma_f32_16x16x32_bf16(As[b % 6][0], bf, acc[0][ot], 0, 0, 0);
        acc[1][ot] = __builtin_amdgcn_mfma_f32_16x16x32_bf16(As[b % 6][1], bf, acc[1][ot], 0, 0, 0);
      }
    }
  };

  // ---- phase 0: barrier covers conn_ps stores + wg_s staging ----
  __syncthreads();
#pragma unroll
  for (int j = 0; j < PFD; ++j) ISSUE(0, j);
  __builtin_amdgcn_sched_barrier(0);
  run_phase(0);

  // ---- transition: all waves done reading wg_s(z0); restage z1 ----
  asm volatile("s_waitcnt lgkmcnt(0)" ::: "memory");
  __builtin_amdgcn_s_barrier();
  __builtin_amdgcn_sched_barrier(0);
  stage(1);
#pragma unroll
  for (int j = 0; j < PFD; ++j) ISSUE(1, j);
  wait_vm(2 * PFD);    // stage(1) drained; 10 gathers in flight
  __builtin_amdgcn_s_barrier();
  __builtin_amdgcn_sched_barrier(0);
  run_phase(1);
#undef ISSUE

  // write f32 partials; piece = blockIdx.y
  constexpr int O = OT * 16;
  float* pbase = part + (size_t)blockIdx.y * n * O;
#pragma unroll
  for (int mt = 0; mt < 2; ++mt)
#pragma unroll
    for (int ot = 0; ot < OT; ++ot)
#pragma unroll
      for (int r = 0; r < 4; ++r) {
        int v = v0 + wave * 32 + mt * 16 + lq * 4 + r;
        if (v < n) pbase[(size_t)v * O + ot * 16 + ln15] = acc[mt][ot][r];
      }
}

// ---------------- finalize GC1: sum 5 partials + bias, relu, bf16 ----------------
__global__ __launch_bounds__(256) void k_fin1(const float* __restrict__ part,
                                              const float* __restrict__ bias,
                                              unsigned short* __restrict__ out, int n) {
  int t = blockIdx.x * 256 + threadIdx.x;
  int total = n * 16;                     // groups of 4 outputs
  if (t >= total) return;
  int base = t * 4;
  int o = base & 63;
  size_t stride = (size_t)n * 64;
  const float* p = part + base;
  f32x4 s = *(const f32x4*)(p);
#pragma unroll
  for (int c = 1; c < 5; ++c) {
    f32x4 q = *(const f32x4*)(p + c * stride);
    s += q;
  }
  const float* b4 = bias + o;
  ushort4 pack;
  pack.x = f2bf(fmaxf(s[0] + b4[0], 0.f));
  pack.y = f2bf(fmaxf(s[1] + b4[1], 0.f));
  pack.z = f2bf(fmaxf(s[2] + b4[2], 0.f));
  pack.w = f2bf(fmaxf(s[3] + b4[3], 0.f));
  *(ushort4*)(out + base) = pack;
}

// ---------------- finalize GC2: sum 8 partials + bias, normalize ----------------
__global__ __launch_bounds__(256) void k_fin2(const float* __restrict__ part,
                                              const float* __restrict__ bias,
                                              float* __restrict__ out, int n) {
  int v = blockIdx.x * 16 + (threadIdx.x >> 4);
  int o = threadIdx.x & 15;
  if (v >= n) return;
  size_t stride = (size_t)n * 32;
  const float* p = part + (size_t)v * 32 + o;
  float a = 0.f, b = 0.f;
#pragma unroll
  for (int c = 0; c < 8; ++c) {
    a += p[c * stride];
    b += p[c * stride + 16];
  }
  a += bias[o];
  b += bias[o + 16];
  float ss = a * a + b * b;
  ss += __shfl_xor(ss, 1);
  ss += __shfl_xor(ss, 2);
  ss += __shfl_xor(ss, 4);
  ss += __shfl_xor(ss, 8);
  float inv = 1.0f / sqrtf(ss);
  out[(size_t)v * 32 + o] = a * inv;
  out[(size_t)v * 32 + 16 + o] = b * inv;
}

extern "C" void kernel_launch(void* const* d_in, const int* in_sizes, int n_in,
                              void* d_out, int out_size, void* d_ws, size_t ws_size,
                              hipStream_t stream) {
  const float* x   = (const float*)d_in[0];
  const float* W1  = (const float*)d_in[1];
  const float* Wg1 = (const float*)d_in[2];
  const float* b1  = (const float*)d_in[3];
  const float* Wg2 = (const float*)d_in[4];
  const float* b2  = (const float*)d_in[5];
  const int*  conn = (const int*)d_in[6];
  int n = in_sizes[0] / 16;

  unsigned char* ws = (unsigned char*)d_ws;
  size_t hb = ((size_t)n * 64 * 2 + 255) & ~(size_t)255;   // bf16 h table bytes
  unsigned short* h1b = (unsigned short*)(ws);
  unsigned short* h2b = (unsigned short*)(ws + hb);
  unsigned char*  w1i = ws + 2 * hb;                        // 80 * 8192
  unsigned char*  w2i = ws + 2 * hb + 80 * 8192;            // 80 * 4096
  float* part = (float*)(ws + 2 * hb + 80 * 8192 + 80 * 4096);  // 5*n*64 / 8*n*32 f32

  k_wimg<<<(80 * 2 * 64 * 4 + 255) / 256, 256, 0, stream>>>(Wg1, w1i, 64, 80 * 2 * 64 * 4);
  k_wimg<<<(80 * 2 * 32 * 4 + 255) / 256, 256, 0, stream>>>(Wg2, w2i, 32, 80 * 2 * 32 * 4);
  k_lin1<<<(n + 255) / 256, 256, 0, stream>>>(x, W1, h1b, n);

  int vt = (n + 255) / 256;
  k_geo5<4, 16><<<dim3(vt, 5), 512, 0, stream>>>(h1b, w1i, conn, part, n);
  k_fin1<<<(n * 16 + 255) / 256, 256, 0, stream>>>(part, b1, h2b, n);
  k_geo5<2, 10><<<dim3(vt, 8), 512, 0, stream>>>(h2b, w2i, conn, part, n);
  k_fin2<<<(n + 15) / 16, 256, 0, stream>>>(part, b2, (float*)d_out, n);
}